// Round 3
// baseline (424.719 us; speedup 1.0000x reference)
//
#include <hip/hip_runtime.h>

#define NN 8192
#define DD 128
#define MAXCLS 64   // max members per class; Binom(8192,1/1024) mean 8 -> P(>64) negligible
#define NCHUNK 8    // j-chunks in the GEMM phase
#define NBLK 512    // fused grid: 2 blocks/CU x 256 CU, co-resident by construction
#define LOG2E 1.4426950408889634f
#define E1    2.718281828459045f   // e^margin, margin = 1

typedef __attribute__((ext_vector_type(8))) short bf16x8;
typedef __attribute__((ext_vector_type(4))) float f32x4;

#if __has_builtin(__builtin_amdgcn_exp2f)
#define EXP2F(x) __builtin_amdgcn_exp2f(x)
#else
#define EXP2F(x) exp2f(x)
#endif

// async global->LDS 16B: per-lane global address, LDS dest = wave-uniform base + lane*16
__device__ __forceinline__ void load16_lds(const unsigned short* g, unsigned short* l) {
    __builtin_amdgcn_global_load_lds(
        (const __attribute__((address_space(1))) unsigned int*)g,
        (__attribute__((address_space(3))) unsigned int*)l,
        16, 0, 0);
}

__device__ __forceinline__ unsigned short f2bf(float x) {
    unsigned u = __float_as_uint(x);
    u = (u + 0x7FFFu + ((u >> 16) & 1u)) >> 16;
    return (unsigned short)u;
}

// ---------------- device-scope grid barrier (512 co-resident blocks) ----------------
// 8 spread sub-counters (64B apart) -> root -> generation bump. Per-thread
// __threadfence() on both sides: release (drain + wbL2) before arrive, acquire (inv)
// after release -- handles cross-XCD L2 non-coherence (Guideline 16). Spin has a
// timeout escape: a co-residency failure yields a WRONG ANSWER (absmax flags it),
// never a hung container.
__device__ __forceinline__ void grid_sync(int* subcnt, int* root, unsigned int* gen) {
    __threadfence();            // all threads: drain own stores, write back L2
    __syncthreads();
    if (threadIdx.x == 0) {
        unsigned int g = __hip_atomic_load(gen, __ATOMIC_RELAXED, __HIP_MEMORY_SCOPE_AGENT);
        int sub = blockIdx.x & 7;
        int v = __hip_atomic_fetch_add(&subcnt[sub * 16], 1, __ATOMIC_ACQ_REL, __HIP_MEMORY_SCOPE_AGENT);
        if (v == (NBLK / 8) - 1) {           // last arrival on this sub-counter
            __hip_atomic_store(&subcnt[sub * 16], 0, __ATOMIC_RELAXED, __HIP_MEMORY_SCOPE_AGENT);
            int r = __hip_atomic_fetch_add(root, 1, __ATOMIC_ACQ_REL, __HIP_MEMORY_SCOPE_AGENT);
            if (r == 7) {                    // whole grid arrived
                __hip_atomic_store(root, 0, __ATOMIC_RELAXED, __HIP_MEMORY_SCOPE_AGENT);
                __hip_atomic_store(gen, g + 1u, __ATOMIC_RELEASE, __HIP_MEMORY_SCOPE_AGENT);
            }
        }
        long long t0 = clock64();
        while (__hip_atomic_load(gen, __ATOMIC_ACQUIRE, __HIP_MEMORY_SCOPE_AGENT) == g) {
            __builtin_amdgcn_s_sleep(1);
            if (clock64() - t0 > (1LL << 24)) break;   // ~7ms escape hatch
        }
    }
    __syncthreads();
    __threadfence();            // acquire side: invalidate so reads miss to LLC
}

// ---------------- fused kernel: convert+bucket | gemm+vsum | pairs | finalize ----------------
__global__ __launch_bounds__(256, 2) void ml_fused_kernel(
    const float* __restrict__ a, const float* __restrict__ b,
    const int* __restrict__ labels,
    unsigned short* __restrict__ abf, unsigned short* __restrict__ bbf,
    int* __restrict__ cnt, int* __restrict__ list,
    float* __restrict__ Vp,
    float* __restrict__ classLoss, int* __restrict__ classCnt,
    float* __restrict__ out,
    int* subcnt, int* root, unsigned int* gen)
{
    __shared__ unsigned short Bs[2][128 * DD];    // 2 x 32 KB; Bs[0] doubles as A-stage
    __shared__ float red[2][64];                  // cross-wave V combine (gemm phase)

    const int tid = threadIdx.x;
    const int bid = blockIdx.x;

    // ================= phase A: fp32->bf16 convert + class bucketing =================
    // (old K0 with 2048 blocks -> 512 blocks x 4 grid-stride iters; cnt pre-zeroed by memset)
#pragma unroll
    for (int it = 0; it < 4; it++) {
        int t = it * (NBLK * 256) + bid * 256 + tid;   // 0 .. 524287
        const float* src = a;
        unsigned short* dst = abf;
        int idx = t;
        float scale = LOG2E;                           // A rows carry the log2e factor
        if (t >= 262144) { src = b; dst = bbf; idx = t - 262144; scale = 1.0f; }
        float4 v = ((const float4*)src)[idx];
        ushort4 o;
        o.x = f2bf(v.x * scale); o.y = f2bf(v.y * scale);
        o.z = f2bf(v.z * scale); o.w = f2bf(v.w * scale);
        ((ushort4*)dst)[idx] = o;
        if (t < NN) {
            int c = labels[t];
            int p = atomicAdd(&cnt[c], 1);
            if (p < MAXCLS) list[c * MAXCLS + p] = t;
        }
    }

    grid_sync(subcnt, root, gen);

    // ================= phase B: flash-style GEMM + unmasked exp2 row-sum =================
    // R13 body verbatim (absmax-0 verified): 128-col B tiles, A register-resident,
    // counted vmcnt(8) across raw barriers, setprio around MFMA cluster.
    {
        const int lane = tid & 63;
        const int wv   = tid >> 6;
        const int row0 = (bid >> 3) * 128;    // 64 row-blocks
        const int j0   = (bid & 7) * 1024;    // 8 j-chunks

        const int lr = lane >> 4;      // staging: row-within-4
        const int sp = lane & 15;      // staging: slot
        const int m  = lane & 15;      // mfma row/col lane
        const int q  = lane >> 4;
        const int xr = m & 7;          // read-side swizzle key

        // ---- prologue: A -> Bs[0], B tile0 -> Bs[1] ----
#pragma unroll
        for (int i = 0; i < 8; i++) {
            int rb = wv * 32 + i * 4;
            int r  = rb + lr;
            int cc = sp ^ (r & 7);
            load16_lds(&abf[(size_t)(row0 + r) * DD + cc * 8], &Bs[0][rb * DD]);
        }
#pragma unroll
        for (int i = 0; i < 8; i++) {
            int rb = wv * 32 + i * 4;
            int r  = rb + lr;
            int cc = sp ^ (r & 7);
            load16_lds(&bbf[(size_t)(j0 + r) * DD + cc * 8], &Bs[1][rb * DD]);
        }
        __syncthreads();               // drains all staging (vmcnt 0): A + tile0 ready

        const int wi = (wv >> 1) * 64;   // row-half of the 128-row block
        const int wj = (wv & 1) * 64;    // col-half of the 128-col tile

        // ---- A fragments -> registers (read once, then Bs[0] is recycled for B) ----
        bf16x8 afr[4][4];
#pragma unroll
        for (int ti = 0; ti < 4; ti++)
#pragma unroll
            for (int ks = 0; ks < 4; ks++) {
                int r   = wi + ti * 16 + m;
                int pos = (ks * 4 + q) ^ xr;
                afr[ti][ks] = *(const bf16x8*)(&Bs[0][r * DD + pos * 8]);
            }
        asm volatile("s_waitcnt lgkmcnt(0)" ::: "memory");  // afr reads done before overwrite
        __syncthreads();

        // issue B tile1 -> Bs[0] (8 outstanding entering the loop)
#pragma unroll
        for (int i = 0; i < 8; i++) {
            int rb = wv * 32 + i * 4;
            int r  = rb + lr;
            int cc = sp ^ (r & 7);
            load16_lds(&bbf[(size_t)(j0 + 128 + r) * DD + cc * 8], &Bs[0][rb * DD]);
        }

        float rs[4][4];
#pragma unroll
        for (int ti = 0; ti < 4; ti++)
#pragma unroll
            for (int rg = 0; rg < 4; rg++) rs[ti][rg] = 0.f;

        const f32x4 zero = {0.f, 0.f, 0.f, 0.f};
        f32x4 acc[4][4];

#define COMPUTE_TILE(BUF)                                                              \
        {                                                                              \
            __builtin_amdgcn_s_setprio(1);                                             \
            _Pragma("unroll")                                                          \
            for (int ks = 0; ks < 4; ks++) {                                           \
                bf16x8 bfr[4];                                                         \
                _Pragma("unroll")                                                      \
                for (int tj = 0; tj < 4; tj++) {                                       \
                    int r   = wj + tj * 16 + m;                                        \
                    int pos = (ks * 4 + q) ^ xr;                                       \
                    bfr[tj] = *(const bf16x8*)(&Bs[BUF][r * DD + pos * 8]);            \
                }                                                                      \
                _Pragma("unroll")                                                      \
                for (int ti = 0; ti < 4; ti++)                                         \
                    _Pragma("unroll")                                                  \
                    for (int tj = 0; tj < 4; tj++)                                     \
                        acc[ti][tj] = __builtin_amdgcn_mfma_f32_16x16x32_bf16(         \
                            afr[ti][ks], bfr[tj], (ks == 0) ? zero : acc[ti][tj],      \
                            0, 0, 0);                                                  \
            }                                                                          \
            __builtin_amdgcn_s_setprio(0);                                             \
        }

#define STAGE_B(JT, BUF)                                                               \
        _Pragma("unroll")                                                              \
        for (int i = 0; i < 8; i++) {                                                  \
            int rb = wv * 32 + i * 4;                                                  \
            int r  = rb + lr;                                                          \
            int cc = sp ^ (r & 7);                                                     \
            load16_lds(&bbf[(size_t)(j0 + (JT) * 128 + r) * DD + cc * 8],              \
                       &Bs[BUF][rb * DD]);                                             \
        }

#define EPILOGUE()                                                                     \
        _Pragma("unroll")                                                              \
        for (int ti = 0; ti < 4; ti++)                                                 \
            _Pragma("unroll")                                                          \
            for (int tj = 0; tj < 4; tj++) {                                           \
                f32x4 c = acc[ti][tj];                                                 \
                rs[ti][0] += EXP2F(c[0]);                                              \
                rs[ti][1] += EXP2F(c[1]);                                              \
                rs[ti][2] += EXP2F(c[2]);                                              \
                rs[ti][3] += EXP2F(c[3]);                                              \
            }

        // ---- steady state: tiles 0..5 (tile jt lives in Bs[(jt+1)&1]) ----
#pragma unroll 2
        for (int jt = 0; jt < 6; jt++) {
            const int cb = (jt + 1) & 1;
            COMPUTE_TILE(cb);
            asm volatile("s_waitcnt lgkmcnt(0)" ::: "memory"); // bfr reads done
            __builtin_amdgcn_s_barrier();                      // all waves done with Bs[cb]
            STAGE_B(jt + 2, cb);                               // issue jt+2 into freed buffer
            EPILOGUE();                                        // register-only; covers flight
            // wait own tile jt+1 loads (8 newest = jt+2's stay IN FLIGHT across barrier)
            asm volatile("s_waitcnt vmcnt(8)" ::: "memory");
            __builtin_amdgcn_s_barrier();
        }
        {   // jt = 6: compute Bs[1]; nothing left to stage
            COMPUTE_TILE(1);
            EPILOGUE();
            asm volatile("s_waitcnt vmcnt(0)" ::: "memory");   // tile7 landed
            __builtin_amdgcn_s_barrier();
        }
        {   // jt = 7: last tile from Bs[0]
            COMPUTE_TILE(0);
            EPILOGUE();
        }

#undef COMPUTE_TILE
#undef STAGE_B
#undef EPILOGUE

        // ---- reduce over the 16 col-lanes ----
#pragma unroll
        for (int ti = 0; ti < 4; ti++)
#pragma unroll
            for (int rg = 0; rg < 4; rg++) {
                float v = rs[ti][rg];
                v += __shfl_xor(v, 1);
                v += __shfl_xor(v, 2);
                v += __shfl_xor(v, 4);
                v += __shfl_xor(v, 8);
                rs[ti][rg] = v;
            }

        // ---- cross-wave combine ----
        if ((wv & 1) == 1 && m == 0) {
#pragma unroll
            for (int ti = 0; ti < 4; ti++)
#pragma unroll
                for (int rg = 0; rg < 4; rg++)
                    red[wv >> 1][ti * 16 + q * 4 + rg] = rs[ti][rg];
        }
        __syncthreads();
        if ((wv & 1) == 0 && m == 0) {
#pragma unroll
            for (int ti = 0; ti < 4; ti++)
#pragma unroll
                for (int rg = 0; rg < 4; rg++) {
                    int rloc = ti * 16 + q * 4 + rg;
                    Vp[(size_t)(bid & 7) * NN + row0 + wi + rloc] = rs[ti][rg] + red[wv >> 1][rloc];
                }
        }
    }

    grid_sync(subcnt, root, gen);

    // ================= phase C: per-class pairs (2 classes per block, LDS reused) =================
    {
        char* sm = (char*)&Bs[0][0];
        int*   mem    = (int*)sm;               // 256 B
        float* sumExp = (float*)(sm + 256);     // 256 B
        float* Vadj   = (float*)(sm + 512);     // 256 B
        float* Sc     = (float*)(sm + 1024);    // 16 KB
        float* ps     = (float*)(sm + 17408);   // 16 B
        int*   cs     = (int*)(sm + 17472);     // 16 B

        for (int ccl = 0; ccl < 2; ccl++) {
            const int c = bid + ccl * NBLK;
            __syncthreads();                    // protect LDS reuse across the two classes

            int mc = cnt[c];
            if (mc > MAXCLS) mc = MAXCLS;

            float vsum = 0.f;
            if (tid < mc) {
                int r = list[c * MAXCLS + tid];
                mem[tid] = r;
#pragma unroll
                for (int jc = 0; jc < NCHUNK; jc++) vsum += Vp[(size_t)jc * NN + r];
            }
            if (tid < MAXCLS) sumExp[tid] = 0.f;
            __syncthreads();

            // phase 1: mc^2 dots (16-lane groups), cache S, accumulate exp sums
            const int g = tid >> 4;
            const int l = tid & 15;
            const int tot1 = mc * mc;
            for (int pp = g; pp < tot1; pp += 16) {
                int i = pp / mc;
                int j = pp - i * mc;
                int ri = mem[i], rj = mem[j];
                const float4* ar = (const float4*)(a + (size_t)ri * DD) + l * 2;
                const float4* br = (const float4*)(b + (size_t)rj * DD) + l * 2;
                float4 a0 = ar[0], a1 = ar[1];
                float4 b0 = br[0], b1 = br[1];
                float s = 0.f;
                s = fmaf(a0.x, b0.x, s); s = fmaf(a0.y, b0.y, s);
                s = fmaf(a0.z, b0.z, s); s = fmaf(a0.w, b0.w, s);
                s = fmaf(a1.x, b1.x, s); s = fmaf(a1.y, b1.y, s);
                s = fmaf(a1.z, b1.z, s); s = fmaf(a1.w, b1.w, s);
                s += __shfl_xor(s, 1);
                s += __shfl_xor(s, 2);
                s += __shfl_xor(s, 4);
                s += __shfl_xor(s, 8);
                if (l == 0) {
                    Sc[i * MAXCLS + j] = s;
                    atomicAdd(&sumExp[i], __expf(s));   // LDS atomic, per-block
                }
            }
            __syncthreads();

            if (tid < mc) Vadj[tid] = E1 * (vsum - sumExp[tid]);
            __syncthreads();

            // phase 2: one thread per ordered pair (i != j)
            float partial = 0.f;
            int   count   = 0;
            for (int pp = tid; pp < tot1; pp += 256) {
                int i = pp / mc;
                int j = pp - i * mc;
                if (i != j) {
                    float h = fmaxf(logf(Vadj[i] + Vadj[j]) - Sc[i * MAXCLS + j], 0.f);
                    partial += h * h;
                    count++;
                }
            }
            for (int off = 32; off > 0; off >>= 1) {
                partial += __shfl_down(partial, off);
                count   += __shfl_down(count, off);
            }
            const int lane = tid & 63, wv = tid >> 6;
            if (lane == 0) { ps[wv] = partial; cs[wv] = count; }
            __syncthreads();
            if (tid == 0) {
                classLoss[c] = ps[0] + ps[1] + ps[2] + ps[3];
                classCnt[c]  = cs[0] + cs[1] + cs[2] + cs[3];
            }
        }
    }

    grid_sync(subcnt, root, gen);

    // ================= phase D: finalize (block 0 only) =================
    if (bid == 0) {
        __shared__ double dred[4];
        __shared__ long long cred[4];
        const int lane = tid & 63, wv = tid >> 6;

        double dls = 0.0;
        long long dct = 0;
        for (int k = tid; k < 1024; k += 256) {
            dls += (double)classLoss[k];
            dct += (long long)classCnt[k];
        }
        for (int off = 32; off > 0; off >>= 1) {
            dls += __shfl_down(dls, off);
            dct += __shfl_down(dct, off);
        }
        if (lane == 0) { dred[wv] = dls; cred[wv] = dct; }
        __syncthreads();
        if (tid == 0) {
            double ls = dred[0] + dred[1] + dred[2] + dred[3];
            long long np = cred[0] + cred[1] + cred[2] + cred[3];
            out[0] = (float)(ls / (2.0 * (double)np));
        }
    }
}

// ---------------- launch ----------------
extern "C" void kernel_launch(void* const* d_in, const int* in_sizes, int n_in,
                              void* d_out, int out_size, void* d_ws, size_t ws_size,
                              hipStream_t stream)
{
    const float* a      = (const float*)d_in[0];
    const float* b      = (const float*)d_in[1];
    const int*   labels = (const int*)d_in[2];
    float* out = (float*)d_out;

    char* ws = (char*)d_ws;
    // ws layout:
    //   [0, 2MB)   a_bf16 (scaled by log2e)    [2MB, 4MB)  b_bf16
    //   base2 = 4MB:
    //     +0       cnt[1024]            4096 B   (memset 0)
    //     +4096    grid-barrier: subcnt[8] @64B stride (512B), root @+512, gen @+576
    //     +8192    classLoss[1024] f32  4096 B
    //     +12288   classCnt[1024] int   4096 B
    //     +16384   list[1024*64]        256 KB
    //     +278528  Vp[8*8192] f32       256 KB
    unsigned short* abf = (unsigned short*)ws;
    unsigned short* bbf = (unsigned short*)(ws + 2097152);
    char*     base2     = ws + 4194304;
    int*      cnt       = (int*)(base2);
    int*      subcnt    = (int*)(base2 + 4096);
    int*      root      = (int*)(base2 + 4096 + 512);
    unsigned int* gen   = (unsigned int*)(base2 + 4096 + 576);
    float*    classLoss = (float*)(base2 + 8192);
    int*      classCnt  = (int*)(base2 + 12288);
    int*      list      = (int*)(base2 + 16384);
    float*    Vp        = (float*)(base2 + 278528);

    (void)hipMemsetAsync(cnt, 0, 8192, stream);   // zeros cnt + barrier state

    ml_fused_kernel<<<NBLK, 256, 0, stream>>>(
        a, b, labels, abf, bbf, cnt, list, Vp, classLoss, classCnt, out,
        subcnt, root, gen);
}

// Round 4
// 144.261 us; speedup vs baseline: 2.9441x; 2.9441x over previous
//
#include <hip/hip_runtime.h>

#define NN 8192
#define DD 128
#define MAXCLS 64   // max members per class; Binom(8192,1/1024) mean 8 -> P(>64) negligible
#define NCHUNK 8    // j-chunks in the GEMM phase
#define NBLK 512    // fused grid: 2 blocks/CU x 256 CU, co-resident by construction
#define LOG2E 1.4426950408889634f
#define E1    2.718281828459045f   // e^margin, margin = 1

typedef __attribute__((ext_vector_type(8))) short bf16x8;
typedef __attribute__((ext_vector_type(4))) float f32x4;

#if __has_builtin(__builtin_amdgcn_exp2f)
#define EXP2F(x) __builtin_amdgcn_exp2f(x)
#else
#define EXP2F(x) exp2f(x)
#endif

// async global->LDS 16B: per-lane global address, LDS dest = wave-uniform base + lane*16
__device__ __forceinline__ void load16_lds(const unsigned short* g, unsigned short* l) {
    __builtin_amdgcn_global_load_lds(
        (const __attribute__((address_space(1))) unsigned int*)g,
        (__attribute__((address_space(3))) unsigned int*)l,
        16, 0, 0);
}

__device__ __forceinline__ unsigned short f2bf(float x) {
    unsigned u = __float_as_uint(x);
    u = (u + 0x7FFFu + ((u >> 16) & 1u)) >> 16;
    return (unsigned short)u;
}

// ---------------- device-scope grid barrier (512 co-resident blocks) ----------------
// R3 POST-MORTEM: the previous version spun on an ACQUIRE agent load -- that emits a
// whole-L1+L2 INVALIDATE PER POLL ITERATION x 512 spinners = continuous cache-
// maintenance storm across all 8 XCDs (kernel 375us, VALUBusy 2.5%). It also ran
// __threadfence() (wbL2+inv) PER THREAD on both sides. This version:
//  * arrive: one RELEASE fetch_add by thread 0 (codegen includes the one required
//    local-XCD L2 writeback; __syncthreads() already drained each wave's stores to L2)
//  * spin: RELAXED agent loads (read at the coherent point, NO cache ops per poll),
//    throttled by s_sleep(2)
//  * exit: ONE ACQUIRE load -> single L1+L2 invalidate per block per sync
// Timeout escape retained: a co-residency failure yields a wrong answer (absmax
// flags it), never a hung container.
__device__ __forceinline__ void grid_sync(int* subcnt, int* root, unsigned int* gen) {
    __syncthreads();            // drains each wave's stores (vmcnt 0) into local L2
    if (threadIdx.x == 0) {
        unsigned int g = __hip_atomic_load(gen, __ATOMIC_RELAXED, __HIP_MEMORY_SCOPE_AGENT);
        int sub = blockIdx.x & 7;
        int v = __hip_atomic_fetch_add(&subcnt[sub * 16], 1, __ATOMIC_RELEASE, __HIP_MEMORY_SCOPE_AGENT);
        if (v == (NBLK / 8) - 1) {           // last arrival on this sub-counter
            __hip_atomic_store(&subcnt[sub * 16], 0, __ATOMIC_RELAXED, __HIP_MEMORY_SCOPE_AGENT);
            int r = __hip_atomic_fetch_add(root, 1, __ATOMIC_RELEASE, __HIP_MEMORY_SCOPE_AGENT);
            if (r == 7) {                    // whole grid arrived
                __hip_atomic_store(root, 0, __ATOMIC_RELAXED, __HIP_MEMORY_SCOPE_AGENT);
                __hip_atomic_store(gen, g + 1u, __ATOMIC_RELEASE, __HIP_MEMORY_SCOPE_AGENT);
            }
        }
        long long t0 = clock64();
        while (__hip_atomic_load(gen, __ATOMIC_RELAXED, __HIP_MEMORY_SCOPE_AGENT) == g) {
            __builtin_amdgcn_s_sleep(2);
            if (clock64() - t0 > (1LL << 24)) break;   // ~7ms escape hatch
        }
        // single acquire: one L1+L2 invalidate so post-barrier reads see remote data
        (void)__hip_atomic_load(gen, __ATOMIC_ACQUIRE, __HIP_MEMORY_SCOPE_AGENT);
    }
    __syncthreads();
}

// ---------------- fused kernel: convert+bucket | gemm+vsum | pairs | finalize ----------------
__global__ __launch_bounds__(256, 2) void ml_fused_kernel(
    const float* __restrict__ a, const float* __restrict__ b,
    const int* __restrict__ labels,
    unsigned short* __restrict__ abf, unsigned short* __restrict__ bbf,
    int* __restrict__ cnt, int* __restrict__ list,
    float* __restrict__ Vp,
    float* __restrict__ classLoss, int* __restrict__ classCnt,
    float* __restrict__ out,
    int* subcnt, int* root, unsigned int* gen)
{
    __shared__ unsigned short Bs[2][128 * DD];    // 2 x 32 KB; Bs[0] doubles as A-stage
    __shared__ float red[2][64];                  // cross-wave V combine (gemm phase)

    const int tid = threadIdx.x;
    const int bid = blockIdx.x;

    // ================= phase A: fp32->bf16 convert + class bucketing =================
#pragma unroll
    for (int it = 0; it < 4; it++) {
        int t = it * (NBLK * 256) + bid * 256 + tid;   // 0 .. 524287
        const float* src = a;
        unsigned short* dst = abf;
        int idx = t;
        float scale = LOG2E;                           // A rows carry the log2e factor
        if (t >= 262144) { src = b; dst = bbf; idx = t - 262144; scale = 1.0f; }
        float4 v = ((const float4*)src)[idx];
        ushort4 o;
        o.x = f2bf(v.x * scale); o.y = f2bf(v.y * scale);
        o.z = f2bf(v.z * scale); o.w = f2bf(v.w * scale);
        ((ushort4*)dst)[idx] = o;
        if (t < NN) {
            int c = labels[t];
            int p = atomicAdd(&cnt[c], 1);
            if (p < MAXCLS) list[c * MAXCLS + p] = t;
        }
    }

    grid_sync(subcnt, root, gen);

    // ================= phase B: flash-style GEMM + unmasked exp2 row-sum =================
    // (absmax-0 verified twice): 128-col B tiles, A register-resident,
    // counted vmcnt(8) across raw barriers, setprio around MFMA cluster.
    {
        const int lane = tid & 63;
        const int wv   = tid >> 6;
        const int row0 = (bid >> 3) * 128;    // 64 row-blocks
        const int j0   = (bid & 7) * 1024;    // 8 j-chunks

        const int lr = lane >> 4;      // staging: row-within-4
        const int sp = lane & 15;      // staging: slot
        const int m  = lane & 15;      // mfma row/col lane
        const int q  = lane >> 4;
        const int xr = m & 7;          // read-side swizzle key

        // ---- prologue: A -> Bs[0], B tile0 -> Bs[1] ----
#pragma unroll
        for (int i = 0; i < 8; i++) {
            int rb = wv * 32 + i * 4;
            int r  = rb + lr;
            int cc = sp ^ (r & 7);
            load16_lds(&abf[(size_t)(row0 + r) * DD + cc * 8], &Bs[0][rb * DD]);
        }
#pragma unroll
        for (int i = 0; i < 8; i++) {
            int rb = wv * 32 + i * 4;
            int r  = rb + lr;
            int cc = sp ^ (r & 7);
            load16_lds(&bbf[(size_t)(j0 + r) * DD + cc * 8], &Bs[1][rb * DD]);
        }
        __syncthreads();               // drains all staging (vmcnt 0): A + tile0 ready

        const int wi = (wv >> 1) * 64;   // row-half of the 128-row block
        const int wj = (wv & 1) * 64;    // col-half of the 128-col tile

        // ---- A fragments -> registers (read once, then Bs[0] is recycled for B) ----
        bf16x8 afr[4][4];
#pragma unroll
        for (int ti = 0; ti < 4; ti++)
#pragma unroll
            for (int ks = 0; ks < 4; ks++) {
                int r   = wi + ti * 16 + m;
                int pos = (ks * 4 + q) ^ xr;
                afr[ti][ks] = *(const bf16x8*)(&Bs[0][r * DD + pos * 8]);
            }
        asm volatile("s_waitcnt lgkmcnt(0)" ::: "memory");  // afr reads done before overwrite
        __syncthreads();

        // issue B tile1 -> Bs[0] (8 outstanding entering the loop)
#pragma unroll
        for (int i = 0; i < 8; i++) {
            int rb = wv * 32 + i * 4;
            int r  = rb + lr;
            int cc = sp ^ (r & 7);
            load16_lds(&bbf[(size_t)(j0 + 128 + r) * DD + cc * 8], &Bs[0][rb * DD]);
        }

        float rs[4][4];
#pragma unroll
        for (int ti = 0; ti < 4; ti++)
#pragma unroll
            for (int rg = 0; rg < 4; rg++) rs[ti][rg] = 0.f;

        const f32x4 zero = {0.f, 0.f, 0.f, 0.f};
        f32x4 acc[4][4];

#define COMPUTE_TILE(BUF)                                                              \
        {                                                                              \
            __builtin_amdgcn_s_setprio(1);                                             \
            _Pragma("unroll")                                                          \
            for (int ks = 0; ks < 4; ks++) {                                           \
                bf16x8 bfr[4];                                                         \
                _Pragma("unroll")                                                      \
                for (int tj = 0; tj < 4; tj++) {                                       \
                    int r   = wj + tj * 16 + m;                                        \
                    int pos = (ks * 4 + q) ^ xr;                                       \
                    bfr[tj] = *(const bf16x8*)(&Bs[BUF][r * DD + pos * 8]);            \
                }                                                                      \
                _Pragma("unroll")                                                      \
                for (int ti = 0; ti < 4; ti++)                                         \
                    _Pragma("unroll")                                                  \
                    for (int tj = 0; tj < 4; tj++)                                     \
                        acc[ti][tj] = __builtin_amdgcn_mfma_f32_16x16x32_bf16(         \
                            afr[ti][ks], bfr[tj], (ks == 0) ? zero : acc[ti][tj],      \
                            0, 0, 0);                                                  \
            }                                                                          \
            __builtin_amdgcn_s_setprio(0);                                             \
        }

#define STAGE_B(JT, BUF)                                                               \
        _Pragma("unroll")                                                              \
        for (int i = 0; i < 8; i++) {                                                  \
            int rb = wv * 32 + i * 4;                                                  \
            int r  = rb + lr;                                                          \
            int cc = sp ^ (r & 7);                                                     \
            load16_lds(&bbf[(size_t)(j0 + (JT) * 128 + r) * DD + cc * 8],              \
                       &Bs[BUF][rb * DD]);                                             \
        }

#define EPILOGUE()                                                                     \
        _Pragma("unroll")                                                              \
        for (int ti = 0; ti < 4; ti++)                                                 \
            _Pragma("unroll")                                                          \
            for (int tj = 0; tj < 4; tj++) {                                           \
                f32x4 c = acc[ti][tj];                                                 \
                rs[ti][0] += EXP2F(c[0]);                                              \
                rs[ti][1] += EXP2F(c[1]);                                              \
                rs[ti][2] += EXP2F(c[2]);                                              \
                rs[ti][3] += EXP2F(c[3]);                                              \
            }

        // ---- steady state: tiles 0..5 (tile jt lives in Bs[(jt+1)&1]) ----
#pragma unroll 2
        for (int jt = 0; jt < 6; jt++) {
            const int cb = (jt + 1) & 1;
            COMPUTE_TILE(cb);
            asm volatile("s_waitcnt lgkmcnt(0)" ::: "memory"); // bfr reads done
            __builtin_amdgcn_s_barrier();                      // all waves done with Bs[cb]
            STAGE_B(jt + 2, cb);                               // issue jt+2 into freed buffer
            EPILOGUE();                                        // register-only; covers flight
            // wait own tile jt+1 loads (8 newest = jt+2's stay IN FLIGHT across barrier)
            asm volatile("s_waitcnt vmcnt(8)" ::: "memory");
            __builtin_amdgcn_s_barrier();
        }
        {   // jt = 6: compute Bs[1]; nothing left to stage
            COMPUTE_TILE(1);
            EPILOGUE();
            asm volatile("s_waitcnt vmcnt(0)" ::: "memory");   // tile7 landed
            __builtin_amdgcn_s_barrier();
        }
        {   // jt = 7: last tile from Bs[0]
            COMPUTE_TILE(0);
            EPILOGUE();
        }

#undef COMPUTE_TILE
#undef STAGE_B
#undef EPILOGUE

        // ---- reduce over the 16 col-lanes ----
#pragma unroll
        for (int ti = 0; ti < 4; ti++)
#pragma unroll
            for (int rg = 0; rg < 4; rg++) {
                float v = rs[ti][rg];
                v += __shfl_xor(v, 1);
                v += __shfl_xor(v, 2);
                v += __shfl_xor(v, 4);
                v += __shfl_xor(v, 8);
                rs[ti][rg] = v;
            }

        // ---- cross-wave combine ----
        if ((wv & 1) == 1 && m == 0) {
#pragma unroll
            for (int ti = 0; ti < 4; ti++)
#pragma unroll
                for (int rg = 0; rg < 4; rg++)
                    red[wv >> 1][ti * 16 + q * 4 + rg] = rs[ti][rg];
        }
        __syncthreads();
        if ((wv & 1) == 0 && m == 0) {
#pragma unroll
            for (int ti = 0; ti < 4; ti++)
#pragma unroll
                for (int rg = 0; rg < 4; rg++) {
                    int rloc = ti * 16 + q * 4 + rg;
                    Vp[(size_t)(bid & 7) * NN + row0 + wi + rloc] = rs[ti][rg] + red[wv >> 1][rloc];
                }
        }
    }

    grid_sync(subcnt, root, gen);

    // ================= phase C: per-class pairs (2 classes per block, LDS reused) =================
    {
        char* sm = (char*)&Bs[0][0];
        int*   mem    = (int*)sm;               // 256 B
        float* sumExp = (float*)(sm + 256);     // 256 B
        float* Vadj   = (float*)(sm + 512);     // 256 B
        float* Sc     = (float*)(sm + 1024);    // 16 KB
        float* ps     = (float*)(sm + 17408);   // 16 B
        int*   cs     = (int*)(sm + 17472);     // 16 B

        for (int ccl = 0; ccl < 2; ccl++) {
            const int c = bid + ccl * NBLK;
            __syncthreads();                    // protect LDS reuse across the two classes

            int mc = cnt[c];
            if (mc > MAXCLS) mc = MAXCLS;

            float vsum = 0.f;
            if (tid < mc) {
                int r = list[c * MAXCLS + tid];
                mem[tid] = r;
#pragma unroll
                for (int jc = 0; jc < NCHUNK; jc++) vsum += Vp[(size_t)jc * NN + r];
            }
            if (tid < MAXCLS) sumExp[tid] = 0.f;
            __syncthreads();

            // phase 1: mc^2 dots (16-lane groups), cache S, accumulate exp sums
            const int g = tid >> 4;
            const int l = tid & 15;
            const int tot1 = mc * mc;
            for (int pp = g; pp < tot1; pp += 16) {
                int i = pp / mc;
                int j = pp - i * mc;
                int ri = mem[i], rj = mem[j];
                const float4* ar = (const float4*)(a + (size_t)ri * DD) + l * 2;
                const float4* br = (const float4*)(b + (size_t)rj * DD) + l * 2;
                float4 a0 = ar[0], a1 = ar[1];
                float4 b0 = br[0], b1 = br[1];
                float s = 0.f;
                s = fmaf(a0.x, b0.x, s); s = fmaf(a0.y, b0.y, s);
                s = fmaf(a0.z, b0.z, s); s = fmaf(a0.w, b0.w, s);
                s = fmaf(a1.x, b1.x, s); s = fmaf(a1.y, b1.y, s);
                s = fmaf(a1.z, b1.z, s); s = fmaf(a1.w, b1.w, s);
                s += __shfl_xor(s, 1);
                s += __shfl_xor(s, 2);
                s += __shfl_xor(s, 4);
                s += __shfl_xor(s, 8);
                if (l == 0) {
                    Sc[i * MAXCLS + j] = s;
                    atomicAdd(&sumExp[i], __expf(s));   // LDS atomic, per-block
                }
            }
            __syncthreads();

            if (tid < mc) Vadj[tid] = E1 * (vsum - sumExp[tid]);
            __syncthreads();

            // phase 2: one thread per ordered pair (i != j)
            float partial = 0.f;
            int   count   = 0;
            for (int pp = tid; pp < tot1; pp += 256) {
                int i = pp / mc;
                int j = pp - i * mc;
                if (i != j) {
                    float h = fmaxf(logf(Vadj[i] + Vadj[j]) - Sc[i * MAXCLS + j], 0.f);
                    partial += h * h;
                    count++;
                }
            }
            for (int off = 32; off > 0; off >>= 1) {
                partial += __shfl_down(partial, off);
                count   += __shfl_down(count, off);
            }
            const int lane = tid & 63, wv = tid >> 6;
            if (lane == 0) { ps[wv] = partial; cs[wv] = count; }
            __syncthreads();
            if (tid == 0) {
                classLoss[c] = ps[0] + ps[1] + ps[2] + ps[3];
                classCnt[c]  = cs[0] + cs[1] + cs[2] + cs[3];
            }
        }
    }

    grid_sync(subcnt, root, gen);

    // ================= phase D: finalize (block 0 only) =================
    if (bid == 0) {
        __shared__ double dred[4];
        __shared__ long long cred[4];
        const int lane = tid & 63, wv = tid >> 6;

        double dls = 0.0;
        long long dct = 0;
        for (int k = tid; k < 1024; k += 256) {
            dls += (double)classLoss[k];
            dct += (long long)classCnt[k];
        }
        for (int off = 32; off > 0; off >>= 1) {
            dls += __shfl_down(dls, off);
            dct += __shfl_down(dct, off);
        }
        if (lane == 0) { dred[wv] = dls; cred[wv] = dct; }
        __syncthreads();
        if (tid == 0) {
            double ls = dred[0] + dred[1] + dred[2] + dred[3];
            long long np = cred[0] + cred[1] + cred[2] + cred[3];
            out[0] = (float)(ls / (2.0 * (double)np));
        }
    }
}

// ---------------- launch ----------------
extern "C" void kernel_launch(void* const* d_in, const int* in_sizes, int n_in,
                              void* d_out, int out_size, void* d_ws, size_t ws_size,
                              hipStream_t stream)
{
    const float* a      = (const float*)d_in[0];
    const float* b      = (const float*)d_in[1];
    const int*   labels = (const int*)d_in[2];
    float* out = (float*)d_out;

    char* ws = (char*)d_ws;
    // ws layout:
    //   [0, 2MB)   a_bf16 (scaled by log2e)    [2MB, 4MB)  b_bf16
    //   base2 = 4MB:
    //     +0       cnt[1024]            4096 B   (memset 0)
    //     +4096    grid-barrier: subcnt[8] @64B stride (512B), root @+512, gen @+576
    //     +8192    classLoss[1024] f32  4096 B
    //     +12288   classCnt[1024] int   4096 B
    //     +16384   list[1024*64]        256 KB
    //     +278528  Vp[8*8192] f32       256 KB
    unsigned short* abf = (unsigned short*)ws;
    unsigned short* bbf = (unsigned short*)(ws + 2097152);
    char*     base2     = ws + 4194304;
    int*      cnt       = (int*)(base2);
    int*      subcnt    = (int*)(base2 + 4096);
    int*      root      = (int*)(base2 + 4096 + 512);
    unsigned int* gen   = (unsigned int*)(base2 + 4096 + 576);
    float*    classLoss = (float*)(base2 + 8192);
    int*      classCnt  = (int*)(base2 + 12288);
    int*      list      = (int*)(base2 + 16384);
    float*    Vp        = (float*)(base2 + 278528);

    (void)hipMemsetAsync(cnt, 0, 8192, stream);   // zeros cnt + barrier state

    ml_fused_kernel<<<NBLK, 256, 0, stream>>>(
        a, b, labels, abf, bbf, cnt, list, Vp, classLoss, classCnt, out,
        subcnt, root, gen);
}

// Round 5
// 121.232 us; speedup vs baseline: 3.5034x; 1.1900x over previous
//
#include <hip/hip_runtime.h>

#define NN 8192
#define DD 128
#define MAXCLS 64   // max members per class; Binom(8192,1/1024) mean 8 -> P(>64) negligible
#define NCHUNK 8    // j-chunks in the GEMM phase
#define NBLK 512    // fused grid: 2 blocks/CU x 256 CU, co-resident by construction
#define LOG2E 1.4426950408889634f
#define E1    2.718281828459045f   // e^margin, margin = 1

typedef __attribute__((ext_vector_type(8))) short bf16x8;
typedef __attribute__((ext_vector_type(4))) float f32x4;

#if __has_builtin(__builtin_amdgcn_exp2f)
#define EXP2F(x) __builtin_amdgcn_exp2f(x)
#else
#define EXP2F(x) exp2f(x)
#endif

// async global->LDS 16B: per-lane global address, LDS dest = wave-uniform base + lane*16
__device__ __forceinline__ void load16_lds(const unsigned short* g, unsigned short* l) {
    __builtin_amdgcn_global_load_lds(
        (const __attribute__((address_space(1))) unsigned int*)g,
        (__attribute__((address_space(3))) unsigned int*)l,
        16, 0, 0);
}

__device__ __forceinline__ unsigned short f2bf(float x) {
    unsigned u = __float_as_uint(x);
    u = (u + 0x7FFFu + ((u >> 16) & 1u)) >> 16;
    return (unsigned short)u;
}

// sc1 write-through store helpers: relaxed AGENT-scope atomic stores bypass L1/L2
// (write at the coherent point). With ALL cross-phase stores sc1, no L2 ever holds
// a dirty global line -> barrier needs no writebacks, and invalidates lose nothing.
__device__ __forceinline__ void st_agent(float* p, float v) {
    __hip_atomic_store(p, v, __ATOMIC_RELAXED, __HIP_MEMORY_SCOPE_AGENT);
}
__device__ __forceinline__ void st_agent(int* p, int v) {
    __hip_atomic_store(p, v, __ATOMIC_RELAXED, __HIP_MEMORY_SCOPE_AGENT);
}
__device__ __forceinline__ void st_agent(unsigned long long* p, unsigned long long v) {
    __hip_atomic_store(p, v, __ATOMIC_RELAXED, __HIP_MEMORY_SCOPE_AGENT);
}

// HW_REG_XCC_ID (id=20) [measured: learn_hip m09]: imm = id | (offset<<6) | ((size-1)<<11)
__device__ __forceinline__ int xcd_id() {
    return (int)(__builtin_amdgcn_s_getreg(20 | (0 << 6) | (31 << 11)) & 7u);
}

// ---------------- device-scope grid barrier, O(8) cache maintenance ----------------
// R4 POST-MORTEM: 512 release-RMWs (one buffer_wbl2 EACH) + 512 acquire loads (one
// L1+L2 buffer_inv EACH) per sync ~= 20us/barrier. This version:
//  * arrivals RELAXED (no cache ops; data already at LLC via sc1 stores)
//  * ONE gen-flip RELEASE store (L2s hold no dirty lines -> wb is a no-op walk)
//  * ONE inv-leader per XCD (generation-tagged atomicExch election): single ACQUIRE
//    load -> one L1+L2 inv per XCD (8 total), then posts done[xcd]; peers spin RELAXED.
// All spins have ~7ms timeout escapes: failure => wrong answer (absmax), never a hang.
__device__ __forceinline__ void grid_sync(int* subcnt, int* root, unsigned int* gen,
                                          unsigned int* gate, unsigned int* done) {
    __syncthreads();   // every wave drains vmcnt -> all sc1 stores complete at LLC
    if (threadIdx.x == 0) {
        unsigned int g = __hip_atomic_load(gen, __ATOMIC_RELAXED, __HIP_MEMORY_SCOPE_AGENT);
        int xcd = xcd_id();
        // elect this XCD's inv-leader for generation g+1: first exchanger wins
        unsigned int prev = __hip_atomic_exchange(&gate[xcd * 16], g + 1u,
                                                  __ATOMIC_RELAXED, __HIP_MEMORY_SCOPE_AGENT);
        bool leader = (prev != g + 1u);
        int sub = blockIdx.x & 7;
        int v = __hip_atomic_fetch_add(&subcnt[sub * 16], 1,
                                       __ATOMIC_RELAXED, __HIP_MEMORY_SCOPE_AGENT);
        if (v == (NBLK / 8) - 1) {           // last arrival on this sub-counter
            __hip_atomic_store(&subcnt[sub * 16], 0, __ATOMIC_RELAXED, __HIP_MEMORY_SCOPE_AGENT);
            int r = __hip_atomic_fetch_add(root, 1, __ATOMIC_RELAXED, __HIP_MEMORY_SCOPE_AGENT);
            if (r == 7) {                    // whole grid arrived
                __hip_atomic_store(root, 0, __ATOMIC_RELAXED, __HIP_MEMORY_SCOPE_AGENT);
                __hip_atomic_store(gen, g + 1u, __ATOMIC_RELEASE, __HIP_MEMORY_SCOPE_AGENT);
            }
        }
        long long t0 = clock64();
        while (__hip_atomic_load(gen, __ATOMIC_RELAXED, __HIP_MEMORY_SCOPE_AGENT) == g) {
            __builtin_amdgcn_s_sleep(2);
            if (clock64() - t0 > (1LL << 24)) break;   // ~7ms escape hatch
        }
        if (leader) {
            // one L1+L2 invalidate for this XCD (L2 is clean by construction)
            (void)__hip_atomic_load(gen, __ATOMIC_ACQUIRE, __HIP_MEMORY_SCOPE_AGENT);
            __hip_atomic_store(&done[xcd * 16], g + 1u, __ATOMIC_RELAXED, __HIP_MEMORY_SCOPE_AGENT);
        } else {
            long long t1 = clock64();
            while (__hip_atomic_load(&done[xcd * 16], __ATOMIC_RELAXED, __HIP_MEMORY_SCOPE_AGENT) != g + 1u) {
                __builtin_amdgcn_s_sleep(2);
                if (clock64() - t1 > (1LL << 24)) break;
            }
        }
    }
    __syncthreads();
}

// ---------------- fused kernel: convert+bucket | gemm+vsum | pairs+finalize ----------------
__global__ __launch_bounds__(256, 2) void ml_fused_kernel(
    const float* __restrict__ a, const float* __restrict__ b,
    const int* __restrict__ labels,
    unsigned short* __restrict__ abf, unsigned short* __restrict__ bbf,
    int* __restrict__ cnt, int* __restrict__ list,
    float* __restrict__ Vp,
    float* __restrict__ classLoss, int* __restrict__ classCnt,
    float* __restrict__ out,
    int* subcnt, int* root, unsigned int* gen,
    unsigned int* gate, unsigned int* done, int* doneCnt)
{
    __shared__ unsigned short Bs[2][128 * DD];    // 2 x 32 KB; Bs[0] doubles as A-stage
    __shared__ float red[2][64];                  // cross-wave V combine (gemm phase)

    const int tid = threadIdx.x;
    const int bid = blockIdx.x;

    // ================= phase A: fp32->bf16 convert + class bucketing =================
#pragma unroll
    for (int it = 0; it < 4; it++) {
        int t = it * (NBLK * 256) + bid * 256 + tid;   // 0 .. 524287
        const float* src = a;
        unsigned short* dst = abf;
        int idx = t;
        float scale = LOG2E;                           // A rows carry the log2e factor
        if (t >= 262144) { src = b; dst = bbf; idx = t - 262144; scale = 1.0f; }
        float4 v = ((const float4*)src)[idx];
        ushort4 o;
        o.x = f2bf(v.x * scale); o.y = f2bf(v.y * scale);
        o.z = f2bf(v.z * scale); o.w = f2bf(v.w * scale);
        union { ushort4 v4; unsigned long long u; } cvt;
        cvt.v4 = o;
        st_agent(((unsigned long long*)dst) + idx, cvt.u);   // sc1: straight to LLC
        if (t < NN) {
            int c = labels[t];
            int p = atomicAdd(&cnt[c], 1);               // agent RMW at LLC
            if (p < MAXCLS) st_agent(&list[c * MAXCLS + p], t);
        }
    }

    grid_sync(subcnt, root, gen, gate, done);

    // ================= phase B: flash-style GEMM + unmasked exp2 row-sum =================
    // (absmax-0 verified 3x): 128-col B tiles, A register-resident, counted vmcnt(8)
    // across raw barriers, setprio around MFMA cluster. Only change: Vp store -> sc1.
    {
        const int lane = tid & 63;
        const int wv   = tid >> 6;
        const int row0 = (bid >> 3) * 128;    // 64 row-blocks
        const int j0   = (bid & 7) * 1024;    // 8 j-chunks

        const int lr = lane >> 4;      // staging: row-within-4
        const int sp = lane & 15;      // staging: slot
        const int m  = lane & 15;      // mfma row/col lane
        const int q  = lane >> 4;
        const int xr = m & 7;          // read-side swizzle key

        // ---- prologue: A -> Bs[0], B tile0 -> Bs[1] ----
#pragma unroll
        for (int i = 0; i < 8; i++) {
            int rb = wv * 32 + i * 4;
            int r  = rb + lr;
            int cc = sp ^ (r & 7);
            load16_lds(&abf[(size_t)(row0 + r) * DD + cc * 8], &Bs[0][rb * DD]);
        }
#pragma unroll
        for (int i = 0; i < 8; i++) {
            int rb = wv * 32 + i * 4;
            int r  = rb + lr;
            int cc = sp ^ (r & 7);
            load16_lds(&bbf[(size_t)(j0 + r) * DD + cc * 8], &Bs[1][rb * DD]);
        }
        __syncthreads();               // drains all staging (vmcnt 0): A + tile0 ready

        const int wi = (wv >> 1) * 64;   // row-half of the 128-row block
        const int wj = (wv & 1) * 64;    // col-half of the 128-col tile

        // ---- A fragments -> registers (read once, then Bs[0] is recycled for B) ----
        bf16x8 afr[4][4];
#pragma unroll
        for (int ti = 0; ti < 4; ti++)
#pragma unroll
            for (int ks = 0; ks < 4; ks++) {
                int r   = wi + ti * 16 + m;
                int pos = (ks * 4 + q) ^ xr;
                afr[ti][ks] = *(const bf16x8*)(&Bs[0][r * DD + pos * 8]);
            }
        asm volatile("s_waitcnt lgkmcnt(0)" ::: "memory");  // afr reads done before overwrite
        __syncthreads();

        // issue B tile1 -> Bs[0] (8 outstanding entering the loop)
#pragma unroll
        for (int i = 0; i < 8; i++) {
            int rb = wv * 32 + i * 4;
            int r  = rb + lr;
            int cc = sp ^ (r & 7);
            load16_lds(&bbf[(size_t)(j0 + 128 + r) * DD + cc * 8], &Bs[0][rb * DD]);
        }

        float rs[4][4];
#pragma unroll
        for (int ti = 0; ti < 4; ti++)
#pragma unroll
            for (int rg = 0; rg < 4; rg++) rs[ti][rg] = 0.f;

        const f32x4 zero = {0.f, 0.f, 0.f, 0.f};
        f32x4 acc[4][4];

#define COMPUTE_TILE(BUF)                                                              \
        {                                                                              \
            __builtin_amdgcn_s_setprio(1);                                             \
            _Pragma("unroll")                                                          \
            for (int ks = 0; ks < 4; ks++) {                                           \
                bf16x8 bfr[4];                                                         \
                _Pragma("unroll")                                                      \
                for (int tj = 0; tj < 4; tj++) {                                       \
                    int r   = wj + tj * 16 + m;                                        \
                    int pos = (ks * 4 + q) ^ xr;                                       \
                    bfr[tj] = *(const bf16x8*)(&Bs[BUF][r * DD + pos * 8]);            \
                }                                                                      \
                _Pragma("unroll")                                                      \
                for (int ti = 0; ti < 4; ti++)                                         \
                    _Pragma("unroll")                                                  \
                    for (int tj = 0; tj < 4; tj++)                                     \
                        acc[ti][tj] = __builtin_amdgcn_mfma_f32_16x16x32_bf16(         \
                            afr[ti][ks], bfr[tj], (ks == 0) ? zero : acc[ti][tj],      \
                            0, 0, 0);                                                  \
            }                                                                          \
            __builtin_amdgcn_s_setprio(0);                                             \
        }

#define STAGE_B(JT, BUF)                                                               \
        _Pragma("unroll")                                                              \
        for (int i = 0; i < 8; i++) {                                                  \
            int rb = wv * 32 + i * 4;                                                  \
            int r  = rb + lr;                                                          \
            int cc = sp ^ (r & 7);                                                     \
            load16_lds(&bbf[(size_t)(j0 + (JT) * 128 + r) * DD + cc * 8],              \
                       &Bs[BUF][rb * DD]);                                             \
        }

#define EPILOGUE()                                                                     \
        _Pragma("unroll")                                                              \
        for (int ti = 0; ti < 4; ti++)                                                 \
            _Pragma("unroll")                                                          \
            for (int tj = 0; tj < 4; tj++) {                                           \
                f32x4 c = acc[ti][tj];                                                 \
                rs[ti][0] += EXP2F(c[0]);                                              \
                rs[ti][1] += EXP2F(c[1]);                                              \
                rs[ti][2] += EXP2F(c[2]);                                              \
                rs[ti][3] += EXP2F(c[3]);                                              \
            }

        // ---- steady state: tiles 0..5 (tile jt lives in Bs[(jt+1)&1]) ----
#pragma unroll 2
        for (int jt = 0; jt < 6; jt++) {
            const int cb = (jt + 1) & 1;
            COMPUTE_TILE(cb);
            asm volatile("s_waitcnt lgkmcnt(0)" ::: "memory"); // bfr reads done
            __builtin_amdgcn_s_barrier();                      // all waves done with Bs[cb]
            STAGE_B(jt + 2, cb);                               // issue jt+2 into freed buffer
            EPILOGUE();                                        // register-only; covers flight
            // wait own tile jt+1 loads (8 newest = jt+2's stay IN FLIGHT across barrier)
            asm volatile("s_waitcnt vmcnt(8)" ::: "memory");
            __builtin_amdgcn_s_barrier();
        }
        {   // jt = 6: compute Bs[1]; nothing left to stage
            COMPUTE_TILE(1);
            EPILOGUE();
            asm volatile("s_waitcnt vmcnt(0)" ::: "memory");   // tile7 landed
            __builtin_amdgcn_s_barrier();
        }
        {   // jt = 7: last tile from Bs[0]
            COMPUTE_TILE(0);
            EPILOGUE();
        }

#undef COMPUTE_TILE
#undef STAGE_B
#undef EPILOGUE

        // ---- reduce over the 16 col-lanes ----
#pragma unroll
        for (int ti = 0; ti < 4; ti++)
#pragma unroll
            for (int rg = 0; rg < 4; rg++) {
                float v = rs[ti][rg];
                v += __shfl_xor(v, 1);
                v += __shfl_xor(v, 2);
                v += __shfl_xor(v, 4);
                v += __shfl_xor(v, 8);
                rs[ti][rg] = v;
            }

        // ---- cross-wave combine ----
        if ((wv & 1) == 1 && m == 0) {
#pragma unroll
            for (int ti = 0; ti < 4; ti++)
#pragma unroll
                for (int rg = 0; rg < 4; rg++)
                    red[wv >> 1][ti * 16 + q * 4 + rg] = rs[ti][rg];
        }
        __syncthreads();
        if ((wv & 1) == 0 && m == 0) {
#pragma unroll
            for (int ti = 0; ti < 4; ti++)
#pragma unroll
                for (int rg = 0; rg < 4; rg++) {
                    int rloc = ti * 16 + q * 4 + rg;
                    st_agent(&Vp[(size_t)(bid & 7) * NN + row0 + wi + rloc],
                             rs[ti][rg] + red[wv >> 1][rloc]);
                }
        }
    }

    grid_sync(subcnt, root, gen, gate, done);

    // ================= phase C: per-class pairs — 2 classes CONCURRENT (half-blocks) ===========
    {
        char* sm = (char*)&Bs[0][0];
        const int h  = tid >> 7;          // half 0/1
        const int ht = tid & 127;         // tid within half
        int*   mem    = (int*)  (sm + h * 18432);           // 256 B
        float* sumExp = (float*)(sm + h * 18432 + 256);     // 256 B
        float* Vadj   = (float*)(sm + h * 18432 + 512);     // 256 B
        float* Sc     = (float*)(sm + h * 18432 + 1024);    // 16 KB
        float* ps     = (float*)(sm + h * 18432 + 17408);   // 8 B (2 waves/half)
        int*   cs     = (int*)  (sm + h * 18432 + 17424);   // 8 B

        const int c = bid * 2 + h;        // classes 0..1023
        int mc = cnt[c];                  // plain load: L2 fresh post-inv
        if (mc > MAXCLS) mc = MAXCLS;

        float vsum = 0.f;
        if (ht < mc) {
            int r = list[c * MAXCLS + ht];
            mem[ht] = r;
#pragma unroll
            for (int jc = 0; jc < NCHUNK; jc++) vsum += Vp[(size_t)jc * NN + r];
        }
        if (ht < MAXCLS) sumExp[ht] = 0.f;
        __syncthreads();   // block-wide; both halves hit it exactly once

        // phase 1: mc^2 dots (8 groups of 16 lanes per half), cache S, exp sums
        const int g = ht >> 4;
        const int l = ht & 15;
        const int tot1 = mc * mc;
        for (int pp = g; pp < tot1; pp += 8) {
            int i = pp / mc;
            int j = pp - i * mc;
            int ri = mem[i], rj = mem[j];
            const float4* ar = (const float4*)(a + (size_t)ri * DD) + l * 2;
            const float4* br = (const float4*)(b + (size_t)rj * DD) + l * 2;
            float4 a0 = ar[0], a1 = ar[1];
            float4 b0 = br[0], b1 = br[1];
            float s = 0.f;
            s = fmaf(a0.x, b0.x, s); s = fmaf(a0.y, b0.y, s);
            s = fmaf(a0.z, b0.z, s); s = fmaf(a0.w, b0.w, s);
            s = fmaf(a1.x, b1.x, s); s = fmaf(a1.y, b1.y, s);
            s = fmaf(a1.z, b1.z, s); s = fmaf(a1.w, b1.w, s);
            s += __shfl_xor(s, 1);
            s += __shfl_xor(s, 2);
            s += __shfl_xor(s, 4);
            s += __shfl_xor(s, 8);
            if (l == 0) {
                Sc[i * MAXCLS + j] = s;
                atomicAdd(&sumExp[i], __expf(s));   // LDS atomic
            }
        }
        __syncthreads();

        if (ht < mc) Vadj[ht] = E1 * (vsum - sumExp[ht]);
        __syncthreads();

        // phase 2: one thread per ordered pair (i != j), 128 threads per half
        float partial = 0.f;
        int   count   = 0;
        for (int pp = ht; pp < tot1; pp += 128) {
            int i = pp / mc;
            int j = pp - i * mc;
            if (i != j) {
                float hg = fmaxf(logf(Vadj[i] + Vadj[j]) - Sc[i * MAXCLS + j], 0.f);
                partial += hg * hg;
                count++;
            }
        }
        for (int off = 32; off > 0; off >>= 1) {
            partial += __shfl_down(partial, off);
            count   += __shfl_down(count, off);
        }
        if ((ht & 63) == 0) { ps[ht >> 6] = partial; cs[ht >> 6] = count; }
        __syncthreads();
        if (ht == 0) {
            st_agent(&classLoss[c], ps[0] + ps[1]);
            st_agent(&classCnt[c],  cs[0] + cs[1]);
        }
    }

    // ================= finalize: last-arriving block reduces (no 3rd barrier) =================
    __syncthreads();   // all waves drain vmcnt -> this block's sc1 stores are at LLC
    __shared__ int amLast;
    if (tid == 0) {
        int d = __hip_atomic_fetch_add(doneCnt, 1, __ATOMIC_RELAXED, __HIP_MEMORY_SCOPE_AGENT);
        amLast = (d == NBLK - 1);
    }
    __syncthreads();
    if (amLast) {
        __shared__ double dred[4];
        __shared__ long long cred[4];
        const int lane = tid & 63, wvv = tid >> 6;
        double dls = 0.0;
        long long dct = 0;
        for (int k = tid; k < 1024; k += 256) {
            dls += (double)__hip_atomic_load(&classLoss[k], __ATOMIC_RELAXED, __HIP_MEMORY_SCOPE_AGENT);
            dct += (long long)__hip_atomic_load(&classCnt[k], __ATOMIC_RELAXED, __HIP_MEMORY_SCOPE_AGENT);
        }
        for (int off = 32; off > 0; off >>= 1) {
            dls += __shfl_down(dls, off);
            dct += __shfl_down(dct, off);
        }
        if (lane == 0) { dred[wvv] = dls; cred[wvv] = dct; }
        __syncthreads();
        if (tid == 0) {
            double ls = dred[0] + dred[1] + dred[2] + dred[3];
            long long np = cred[0] + cred[1] + cred[2] + cred[3];
            out[0] = (float)(ls / (2.0 * (double)np));
        }
    }
}

// ---------------- launch ----------------
extern "C" void kernel_launch(void* const* d_in, const int* in_sizes, int n_in,
                              void* d_out, int out_size, void* d_ws, size_t ws_size,
                              hipStream_t stream)
{
    const float* a      = (const float*)d_in[0];
    const float* b      = (const float*)d_in[1];
    const int*   labels = (const int*)d_in[2];
    float* out = (float*)d_out;

    char* ws = (char*)d_ws;
    // ws layout:
    //   [0, 2MB)   a_bf16 (scaled by log2e)    [2MB, 4MB)  b_bf16
    //   base2 = 4MB (first 8KB memset to 0):
    //     +0     cnt[1024]              4096 B
    //     +4096  subcnt[8] @64B stride   512 B
    //     +4608  root(4), gen(4)
    //     +4672  gate[8] @64B stride     512 B
    //     +5184  done[8] @64B stride     512 B
    //     +5696  doneCnt(4)
    //     +8192  classLoss[1024] f32    4096 B
    //     +12288 classCnt[1024] int     4096 B
    //     +16384 list[1024*64]          256 KB
    //     +278528 Vp[8*8192] f32        256 KB
    unsigned short* abf = (unsigned short*)ws;
    unsigned short* bbf = (unsigned short*)(ws + 2097152);
    char*     base2     = ws + 4194304;
    int*      cnt       = (int*)(base2);
    int*      subcnt    = (int*)(base2 + 4096);
    int*      root      = (int*)(base2 + 4608);
    unsigned int* gen   = (unsigned int*)(base2 + 4612);
    unsigned int* gate  = (unsigned int*)(base2 + 4672);
    unsigned int* done  = (unsigned int*)(base2 + 5184);
    int*      doneCnt   = (int*)(base2 + 5696);
    float*    classLoss = (float*)(base2 + 8192);
    int*      classCnt  = (int*)(base2 + 12288);
    int*      list      = (int*)(base2 + 16384);
    float*    Vp        = (float*)(base2 + 278528);

    (void)hipMemsetAsync(cnt, 0, 8192, stream);   // zeros cnt + all barrier state

    ml_fused_kernel<<<NBLK, 256, 0, stream>>>(
        a, b, labels, abf, bbf, cnt, list, Vp, classLoss, classCnt, out,
        subcnt, root, gen, gate, done, doneCnt);
}

// Round 6
// 111.726 us; speedup vs baseline: 3.8014x; 1.0851x over previous
//
#include <hip/hip_runtime.h>

#define NN 8192
#define DD 128
#define MAXCLS 64   // max members per class; Binom(8192,1/1024) mean 8 -> P(>64) negligible
#define NCHUNK 8    // j-chunks in the GEMM phase
#define NBLK 512    // fused grid: 2 blocks/CU x 256 CU, co-resident by construction
#define LOG2E 1.4426950408889634f
#define E1    2.718281828459045f   // e^margin, margin = 1

typedef __attribute__((ext_vector_type(8))) short bf16x8;
typedef __attribute__((ext_vector_type(4))) float f32x4;

#if __has_builtin(__builtin_amdgcn_exp2f)
#define EXP2F(x) __builtin_amdgcn_exp2f(x)
#else
#define EXP2F(x) exp2f(x)
#endif

// async global->LDS 16B: per-lane global address, LDS dest = wave-uniform base + lane*16
__device__ __forceinline__ void load16_lds(const unsigned short* g, unsigned short* l) {
    __builtin_amdgcn_global_load_lds(
        (const __attribute__((address_space(1))) unsigned int*)g,
        (__attribute__((address_space(3))) unsigned int*)l,
        16, 0, 0);
}

__device__ __forceinline__ unsigned short f2bf(float x) {
    unsigned u = __float_as_uint(x);
    u = (u + 0x7FFFu + ((u >> 16) & 1u)) >> 16;
    return (unsigned short)u;
}

// sc1 write-through stores: relaxed AGENT-scope atomic stores write at the coherent
// point (LLC) and never allocate in L1/L2. ALL cross-phase data uses these ->
// no L2 ever holds a dirty OR stale copy of cross-phase data (first read by a
// consumer is an L2 miss that fetches fresh LLC data) -> barriers need NO cache
// maintenance at all (R5's leader-inv removed).
__device__ __forceinline__ void st_agent(float* p, float v) {
    __hip_atomic_store(p, v, __ATOMIC_RELAXED, __HIP_MEMORY_SCOPE_AGENT);
}
__device__ __forceinline__ void st_agent(int* p, int v) {
    __hip_atomic_store(p, v, __ATOMIC_RELAXED, __HIP_MEMORY_SCOPE_AGENT);
}
__device__ __forceinline__ void st_agent(unsigned int* p, unsigned int v) {
    __hip_atomic_store(p, v, __ATOMIC_RELAXED, __HIP_MEMORY_SCOPE_AGENT);
}
__device__ __forceinline__ void st_agent(unsigned long long* p, unsigned long long v) {
    __hip_atomic_store(p, v, __ATOMIC_RELAXED, __HIP_MEMORY_SCOPE_AGENT);
}
__device__ __forceinline__ unsigned int ld_agent(const unsigned int* p) {
    return __hip_atomic_load(p, __ATOMIC_RELAXED, __HIP_MEMORY_SCOPE_AGENT);
}

// HW_REG_XCC_ID (id=20) [measured: learn_hip m09]. Correctness does NOT depend on
// this value being right -- only on per-block consistency (grouping key).
__device__ __forceinline__ int xcd_id() {
    return (int)(__builtin_amdgcn_s_getreg(20 | (0 << 6) | (31 << 11)) & 7u);
}

// ---------------- device-scope grid barrier, zero cache maintenance ----------------
// R5 POST-MORTEM: residual barrier cost was LLC same-line serialization (root/gen/
// gate shared one 128B line; 64B-strided counters aliased pairwise; 512 gate RMWs
// per barrier) plus an unnecessary leader-invalidate. This version:
//  * all barrier words on DISTINCT 128B lines (stride 32 ints)
//  * relay (one per XCD) claimed ONCE at kernel start, not per barrier
//  * arrivals: 64 relaxed RMWs per line across 8 lines; NO release, NO acquire,
//    NO inv (sound because all cross-phase data is sc1 + first-touch-after-sync;
//    data stores are vmcnt-drained by __syncthreads before the arrival RMW issues)
//  * 8 relays poll gen; peers poll a per-XCD 128B line (<=64 pollers/line)
// All spins carry ~7ms timeout escapes: failure => wrong answer (absmax), never a hang.
__device__ __forceinline__ void grid_sync(int* subcnt, int* root, unsigned int* gen,
                                          unsigned int* doneg, int relay, int myxcd,
                                          int sub) {
    __syncthreads();   // every wave drains vmcnt -> all sc1 stores complete at LLC
    if (threadIdx.x == 0) {
        unsigned int g = ld_agent(gen);   // gen can't advance past g before we arrive
        int v = __hip_atomic_fetch_add(&subcnt[sub * 32], 1,
                                       __ATOMIC_RELAXED, __HIP_MEMORY_SCOPE_AGENT);
        if (v == (NBLK / 8) - 1) {           // last arrival on this sub-counter
            __hip_atomic_store(&subcnt[sub * 32], 0, __ATOMIC_RELAXED, __HIP_MEMORY_SCOPE_AGENT);
            int r = __hip_atomic_fetch_add(root, 1, __ATOMIC_RELAXED, __HIP_MEMORY_SCOPE_AGENT);
            if (r == 7) {                    // whole grid arrived
                __hip_atomic_store(root, 0, __ATOMIC_RELAXED, __HIP_MEMORY_SCOPE_AGENT);
                st_agent(gen, g + 1u);
            }
        }
        if (relay) {
            long long t0 = clock64();
            while (ld_agent(gen) == g) {
                __builtin_amdgcn_s_sleep(1);
                if (clock64() - t0 > (1LL << 24)) break;   // ~7ms escape hatch
            }
            st_agent(&doneg[myxcd * 32], g + 1u);          // repost on per-XCD line
        } else {
            long long t1 = clock64();
            while ((int)(ld_agent(&doneg[myxcd * 32]) - (g + 1u)) < 0) {
                __builtin_amdgcn_s_sleep(1);
                if (clock64() - t1 > (1LL << 24)) break;
            }
        }
    }
    __syncthreads();
}

// ---------------- fused kernel: convert+bucket | gemm+vsum | pairs | finalize ----------------
__global__ __launch_bounds__(256, 2) void ml_fused_kernel(
    const float* __restrict__ a, const float* __restrict__ b,
    const int* __restrict__ labels,
    unsigned short* __restrict__ abf, unsigned short* __restrict__ bbf,
    int* __restrict__ cnt, int* __restrict__ list,
    float* __restrict__ Vp,
    float* __restrict__ classLoss, int* __restrict__ classCnt,
    float* __restrict__ out,
    int* subcnt, int* root, unsigned int* gen,
    int* claim, unsigned int* doneg)
{
    __shared__ unsigned short Bs[2][128 * DD];    // 2 x 32 KB; Bs[0] doubles as A-stage
    __shared__ float red[2][64];                  // cross-wave V combine (gemm phase)

    const int tid = threadIdx.x;
    const int bid = blockIdx.x;
    const int sub = bid & 7;

    // one-time relay claim (first block per XCD value wins); only thread 0's copy matters
    int relay = 0, myxcd = 0;
    if (tid == 0) {
        myxcd = xcd_id();
        relay = (__hip_atomic_fetch_add(&claim[myxcd * 32], 1,
                                        __ATOMIC_RELAXED, __HIP_MEMORY_SCOPE_AGENT) == 0);
    }

    // ================= phase A: fp32->bf16 convert + class bucketing =================
#pragma unroll
    for (int it = 0; it < 4; it++) {
        int t = it * (NBLK * 256) + bid * 256 + tid;   // 0 .. 524287
        const float* src = a;
        unsigned short* dst = abf;
        int idx = t;
        float scale = LOG2E;                           // A rows carry the log2e factor
        if (t >= 262144) { src = b; dst = bbf; idx = t - 262144; scale = 1.0f; }
        float4 v = ((const float4*)src)[idx];
        ushort4 o;
        o.x = f2bf(v.x * scale); o.y = f2bf(v.y * scale);
        o.z = f2bf(v.z * scale); o.w = f2bf(v.w * scale);
        union { ushort4 v4; unsigned long long u; } cvt;
        cvt.v4 = o;
        st_agent(((unsigned long long*)dst) + idx, cvt.u);   // sc1: straight to LLC
        if (t < NN) {
            int c = labels[t];
            int p = atomicAdd(&cnt[c], 1);               // device-scope RMW at LLC
            if (p < MAXCLS) st_agent(&list[c * MAXCLS + p], t);
        }
    }

    grid_sync(subcnt, root, gen, doneg, relay, myxcd, sub);

    // ================= phase B: flash-style GEMM + unmasked exp2 row-sum =================
    // (absmax-0 verified 4x): 128-col B tiles, A register-resident, counted vmcnt(8)
    // across raw barriers, setprio around MFMA cluster. Vp stores sc1.
    {
        const int lane = tid & 63;
        const int wv   = tid >> 6;
        const int row0 = (bid >> 3) * 128;    // 64 row-blocks
        const int j0   = (bid & 7) * 1024;    // 8 j-chunks

        const int lr = lane >> 4;      // staging: row-within-4
        const int sp = lane & 15;      // staging: slot
        const int m  = lane & 15;      // mfma row/col lane
        const int q  = lane >> 4;
        const int xr = m & 7;          // read-side swizzle key

        // ---- prologue: A -> Bs[0], B tile0 -> Bs[1] ----
#pragma unroll
        for (int i = 0; i < 8; i++) {
            int rb = wv * 32 + i * 4;
            int r  = rb + lr;
            int cc = sp ^ (r & 7);
            load16_lds(&abf[(size_t)(row0 + r) * DD + cc * 8], &Bs[0][rb * DD]);
        }
#pragma unroll
        for (int i = 0; i < 8; i++) {
            int rb = wv * 32 + i * 4;
            int r  = rb + lr;
            int cc = sp ^ (r & 7);
            load16_lds(&bbf[(size_t)(j0 + r) * DD + cc * 8], &Bs[1][rb * DD]);
        }
        __syncthreads();               // drains all staging (vmcnt 0): A + tile0 ready

        const int wi = (wv >> 1) * 64;   // row-half of the 128-row block
        const int wj = (wv & 1) * 64;    // col-half of the 128-col tile

        // ---- A fragments -> registers (read once, then Bs[0] is recycled for B) ----
        bf16x8 afr[4][4];
#pragma unroll
        for (int ti = 0; ti < 4; ti++)
#pragma unroll
            for (int ks = 0; ks < 4; ks++) {
                int r   = wi + ti * 16 + m;
                int pos = (ks * 4 + q) ^ xr;
                afr[ti][ks] = *(const bf16x8*)(&Bs[0][r * DD + pos * 8]);
            }
        asm volatile("s_waitcnt lgkmcnt(0)" ::: "memory");  // afr reads done before overwrite
        __syncthreads();

        // issue B tile1 -> Bs[0] (8 outstanding entering the loop)
#pragma unroll
        for (int i = 0; i < 8; i++) {
            int rb = wv * 32 + i * 4;
            int r  = rb + lr;
            int cc = sp ^ (r & 7);
            load16_lds(&bbf[(size_t)(j0 + 128 + r) * DD + cc * 8], &Bs[0][rb * DD]);
        }

        float rs[4][4];
#pragma unroll
        for (int ti = 0; ti < 4; ti++)
#pragma unroll
            for (int rg = 0; rg < 4; rg++) rs[ti][rg] = 0.f;

        const f32x4 zero = {0.f, 0.f, 0.f, 0.f};
        f32x4 acc[4][4];

#define COMPUTE_TILE(BUF)                                                              \
        {                                                                              \
            __builtin_amdgcn_s_setprio(1);                                             \
            _Pragma("unroll")                                                          \
            for (int ks = 0; ks < 4; ks++) {                                           \
                bf16x8 bfr[4];                                                         \
                _Pragma("unroll")                                                      \
                for (int tj = 0; tj < 4; tj++) {                                       \
                    int r   = wj + tj * 16 + m;                                        \
                    int pos = (ks * 4 + q) ^ xr;                                       \
                    bfr[tj] = *(const bf16x8*)(&Bs[BUF][r * DD + pos * 8]);            \
                }                                                                      \
                _Pragma("unroll")                                                      \
                for (int ti = 0; ti < 4; ti++)                                         \
                    _Pragma("unroll")                                                  \
                    for (int tj = 0; tj < 4; tj++)                                     \
                        acc[ti][tj] = __builtin_amdgcn_mfma_f32_16x16x32_bf16(         \
                            afr[ti][ks], bfr[tj], (ks == 0) ? zero : acc[ti][tj],      \
                            0, 0, 0);                                                  \
            }                                                                          \
            __builtin_amdgcn_s_setprio(0);                                             \
        }

#define STAGE_B(JT, BUF)                                                               \
        _Pragma("unroll")                                                              \
        for (int i = 0; i < 8; i++) {                                                  \
            int rb = wv * 32 + i * 4;                                                  \
            int r  = rb + lr;                                                          \
            int cc = sp ^ (r & 7);                                                     \
            load16_lds(&bbf[(size_t)(j0 + (JT) * 128 + r) * DD + cc * 8],              \
                       &Bs[BUF][rb * DD]);                                             \
        }

#define EPILOGUE()                                                                     \
        _Pragma("unroll")                                                              \
        for (int ti = 0; ti < 4; ti++)                                                 \
            _Pragma("unroll")                                                          \
            for (int tj = 0; tj < 4; tj++) {                                           \
                f32x4 c = acc[ti][tj];                                                 \
                rs[ti][0] += EXP2F(c[0]);                                              \
                rs[ti][1] += EXP2F(c[1]);                                              \
                rs[ti][2] += EXP2F(c[2]);                                              \
                rs[ti][3] += EXP2F(c[3]);                                              \
            }

        // ---- steady state: tiles 0..5 (tile jt lives in Bs[(jt+1)&1]) ----
#pragma unroll 2
        for (int jt = 0; jt < 6; jt++) {
            const int cb = (jt + 1) & 1;
            COMPUTE_TILE(cb);
            asm volatile("s_waitcnt lgkmcnt(0)" ::: "memory"); // bfr reads done
            __builtin_amdgcn_s_barrier();                      // all waves done with Bs[cb]
            STAGE_B(jt + 2, cb);                               // issue jt+2 into freed buffer
            EPILOGUE();                                        // register-only; covers flight
            // wait own tile jt+1 loads (8 newest = jt+2's stay IN FLIGHT across barrier)
            asm volatile("s_waitcnt vmcnt(8)" ::: "memory");
            __builtin_amdgcn_s_barrier();
        }
        {   // jt = 6: compute Bs[1]; nothing left to stage
            COMPUTE_TILE(1);
            EPILOGUE();
            asm volatile("s_waitcnt vmcnt(0)" ::: "memory");   // tile7 landed
            __builtin_amdgcn_s_barrier();
        }
        {   // jt = 7: last tile from Bs[0]
            COMPUTE_TILE(0);
            EPILOGUE();
        }

#undef COMPUTE_TILE
#undef STAGE_B
#undef EPILOGUE

        // ---- reduce over the 16 col-lanes ----
#pragma unroll
        for (int ti = 0; ti < 4; ti++)
#pragma unroll
            for (int rg = 0; rg < 4; rg++) {
                float v = rs[ti][rg];
                v += __shfl_xor(v, 1);
                v += __shfl_xor(v, 2);
                v += __shfl_xor(v, 4);
                v += __shfl_xor(v, 8);
                rs[ti][rg] = v;
            }

        // ---- cross-wave combine ----
        if ((wv & 1) == 1 && m == 0) {
#pragma unroll
            for (int ti = 0; ti < 4; ti++)
#pragma unroll
                for (int rg = 0; rg < 4; rg++)
                    red[wv >> 1][ti * 16 + q * 4 + rg] = rs[ti][rg];
        }
        __syncthreads();
        if ((wv & 1) == 0 && m == 0) {
#pragma unroll
            for (int ti = 0; ti < 4; ti++)
#pragma unroll
                for (int rg = 0; rg < 4; rg++) {
                    int rloc = ti * 16 + q * 4 + rg;
                    st_agent(&Vp[(size_t)(bid & 7) * NN + row0 + wi + rloc],
                             rs[ti][rg] + red[wv >> 1][rloc]);
                }
        }
    }

    grid_sync(subcnt, root, gen, doneg, relay, myxcd, sub);

    // ================= phase C: per-class pairs — 2 classes CONCURRENT (half-blocks) ===========
    {
        char* sm = (char*)&Bs[0][0];
        const int h  = tid >> 7;          // half 0/1
        const int ht = tid & 127;         // tid within half
        int*   mem    = (int*)  (sm + h * 18432);           // 256 B
        float* sumExp = (float*)(sm + h * 18432 + 256);     // 256 B
        float* Vadj   = (float*)(sm + h * 18432 + 512);     // 256 B
        float* Sc     = (float*)(sm + h * 18432 + 1024);    // 16 KB
        float* ps     = (float*)(sm + h * 18432 + 17408);   // 8 B (2 waves/half)
        int*   cs     = (int*)  (sm + h * 18432 + 17424);   // 8 B

        const int c = bid * 2 + h;        // classes 0..1023
        int mc = cnt[c];                  // first in-kernel read -> L2 miss -> fresh LLC
        if (mc > MAXCLS) mc = MAXCLS;

        float vsum = 0.f;
        if (ht < mc) {
            int r = list[c * MAXCLS + ht];
            mem[ht] = r;
#pragma unroll
            for (int jc = 0; jc < NCHUNK; jc++) vsum += Vp[(size_t)jc * NN + r];
        }
        if (ht < MAXCLS) sumExp[ht] = 0.f;
        __syncthreads();   // block-wide; both halves hit it exactly once

        // phase 1: mc^2 dots (8 groups of 16 lanes per half), cache S, exp sums
        const int g = ht >> 4;
        const int l = ht & 15;
        const int tot1 = mc * mc;
        for (int pp = g; pp < tot1; pp += 8) {
            int i = pp / mc;
            int j = pp - i * mc;
            int ri = mem[i], rj = mem[j];
            const float4* ar = (const float4*)(a + (size_t)ri * DD) + l * 2;
            const float4* br = (const float4*)(b + (size_t)rj * DD) + l * 2;
            float4 a0 = ar[0], a1 = ar[1];
            float4 b0 = br[0], b1 = br[1];
            float s = 0.f;
            s = fmaf(a0.x, b0.x, s); s = fmaf(a0.y, b0.y, s);
            s = fmaf(a0.z, b0.z, s); s = fmaf(a0.w, b0.w, s);
            s = fmaf(a1.x, b1.x, s); s = fmaf(a1.y, b1.y, s);
            s = fmaf(a1.z, b1.z, s); s = fmaf(a1.w, b1.w, s);
            s += __shfl_xor(s, 1);
            s += __shfl_xor(s, 2);
            s += __shfl_xor(s, 4);
            s += __shfl_xor(s, 8);
            if (l == 0) {
                Sc[i * MAXCLS + j] = s;
                atomicAdd(&sumExp[i], __expf(s));   // LDS atomic
            }
        }
        __syncthreads();

        if (ht < mc) Vadj[ht] = E1 * (vsum - sumExp[ht]);
        __syncthreads();

        // phase 2: one thread per ordered pair (i != j), 128 threads per half
        float partial = 0.f;
        int   count   = 0;
        for (int pp = ht; pp < tot1; pp += 128) {
            int i = pp / mc;
            int j = pp - i * mc;
            if (i != j) {
                float hg = fmaxf(logf(Vadj[i] + Vadj[j]) - Sc[i * MAXCLS + j], 0.f);
                partial += hg * hg;
                count++;
            }
        }
        for (int off = 32; off > 0; off >>= 1) {
            partial += __shfl_down(partial, off);
            count   += __shfl_down(count, off);
        }
        if ((ht & 63) == 0) { ps[ht >> 6] = partial; cs[ht >> 6] = count; }
        __syncthreads();
        if (ht == 0) {
            st_agent(&classLoss[c], ps[0] + ps[1]);
            st_agent(&classCnt[c],  cs[0] + cs[1]);
        }
    }

    // ========== finalize: spread arrival tree; LAST block reduces, others exit ==========
    __syncthreads();   // all waves drain vmcnt -> this block's sc1 stores are at LLC
    __shared__ int amLast;
    if (tid == 0) {
        int last = 0;
        int v = __hip_atomic_fetch_add(&subcnt[sub * 32], 1,
                                       __ATOMIC_RELAXED, __HIP_MEMORY_SCOPE_AGENT);
        if (v == (NBLK / 8) - 1) {
            __hip_atomic_store(&subcnt[sub * 32], 0, __ATOMIC_RELAXED, __HIP_MEMORY_SCOPE_AGENT);
            int r = __hip_atomic_fetch_add(root, 1, __ATOMIC_RELAXED, __HIP_MEMORY_SCOPE_AGENT);
            if (r == 7) { __hip_atomic_store(root, 0, __ATOMIC_RELAXED, __HIP_MEMORY_SCOPE_AGENT); last = 1; }
        }
        amLast = last;
    }
    __syncthreads();
    if (amLast) {
        __shared__ double dred[4];
        __shared__ long long cred[4];
        const int lane = tid & 63, wvv = tid >> 6;
        double dls = 0.0;
        long long dct = 0;
        for (int k = tid; k < 1024; k += 256) {
            dls += (double)__hip_atomic_load(&classLoss[k], __ATOMIC_RELAXED, __HIP_MEMORY_SCOPE_AGENT);
            dct += (long long)__hip_atomic_load(&classCnt[k], __ATOMIC_RELAXED, __HIP_MEMORY_SCOPE_AGENT);
        }
        for (int off = 32; off > 0; off >>= 1) {
            dls += __shfl_down(dls, off);
            dct += __shfl_down(dct, off);
        }
        if (lane == 0) { dred[wvv] = dls; cred[wvv] = dct; }
        __syncthreads();
        if (tid == 0) {
            double ls = dred[0] + dred[1] + dred[2] + dred[3];
            long long np = cred[0] + cred[1] + cred[2] + cred[3];
            out[0] = (float)(ls / (2.0 * (double)np));
        }
    }
}

// ---------------- launch ----------------
extern "C" void kernel_launch(void* const* d_in, const int* in_sizes, int n_in,
                              void* d_out, int out_size, void* d_ws, size_t ws_size,
                              hipStream_t stream)
{
    const float* a      = (const float*)d_in[0];
    const float* b      = (const float*)d_in[1];
    const int*   labels = (const int*)d_in[2];
    float* out = (float*)d_out;

    char* ws = (char*)d_ws;
    // ws layout:
    //   [0, 2MB)   a_bf16 (scaled by log2e)    [2MB, 4MB)  b_bf16
    //   base2 = 4MB (first 8KB memset to 0); every barrier word on its OWN 128B line:
    //     +0     cnt[1024]              4096 B
    //     +4096  subcnt[8]  @128B stride  1 KB  -> [4096, 5120)
    //     +5120  root
    //     +5248  gen
    //     +5376  claim[8]   @128B stride  1 KB  -> [5376, 6400)
    //     +6400  doneg[8]   @128B stride  1 KB  -> [6400, 7424)
    //     +8192  classLoss[1024] f32    4096 B
    //     +12288 classCnt[1024] int     4096 B
    //     +16384 list[1024*64]          256 KB
    //     +278528 Vp[8*8192] f32        256 KB
    unsigned short* abf = (unsigned short*)ws;
    unsigned short* bbf = (unsigned short*)(ws + 2097152);
    char*     base2     = ws + 4194304;
    int*      cnt       = (int*)(base2);
    int*      subcnt    = (int*)(base2 + 4096);
    int*      root      = (int*)(base2 + 5120);
    unsigned int* gen   = (unsigned int*)(base2 + 5248);
    int*      claim     = (int*)(base2 + 5376);
    unsigned int* doneg = (unsigned int*)(base2 + 6400);
    float*    classLoss = (float*)(base2 + 8192);
    int*      classCnt  = (int*)(base2 + 12288);
    int*      list      = (int*)(base2 + 16384);
    float*    Vp        = (float*)(base2 + 278528);

    (void)hipMemsetAsync(cnt, 0, 8192, stream);   // zeros cnt + all barrier state

    ml_fused_kernel<<<NBLK, 256, 0, stream>>>(
        a, b, labels, abf, bbf, cnt, list, Vp, classLoss, classCnt, out,
        subcnt, root, gen, claim, doneg);
}